// Round 1
// baseline (2951.483 us; speedup 1.0000x reference)
//
#include <hip/hip_runtime.h>
#include <hip/hip_bf16.h>
#include <cstdint>
#include <cstddef>

#define L_TOK 577
#define DM 256
#define DI 512
#define DS_ 64
#define NROWS (16*577)      // 9232
#define PROWS (16*576)      // 9216

typedef float f32x4v __attribute__((ext_vector_type(4)));
typedef __bf16 bf16x8 __attribute__((ext_vector_type(8)));

// ---------------- GEMM: C[M,N] = A[M,K] * B[N,K]^T  (+C if beta) -------------
// fp32 in memory, converted to bf16 during LDS staging; fp32 MFMA accumulate.
__global__ __launch_bounds__(256)
void k_gemm(const float* __restrict__ A, int lda,
            const float* __restrict__ B, int ldb,
            float* __restrict__ C, int ldc,
            int M, int N, int K, int beta)
{
    __shared__ char sA[128*64*2];   // 128 rows x 64 bf16 (XOR-swizzled 16B slots)
    __shared__ char sB[128*64*2];
    const int tid  = threadIdx.x;
    const int lane = tid & 63;
    const int wave = tid >> 6;
    const int wr = wave >> 1, wc = wave & 1;
    const int tm = blockIdx.y * 128, tn = blockIdx.x * 128;

    f32x4v acc[4][4];
#pragma unroll
    for (int m = 0; m < 4; ++m)
#pragma unroll
        for (int n = 0; n < 4; ++n) acc[m][n] = (f32x4v){0.f, 0.f, 0.f, 0.f};

    const int nk = K >> 6;
    for (int kt = 0; kt < nk; ++kt) {
        const int k0 = kt << 6;
        __syncthreads();
        // stage A tile (128x64 f32 -> bf16), 16B chunks: c = row*8 + slot
#pragma unroll
        for (int i = 0; i < 4; ++i) {
            int c = tid + (i << 8);
            int row = c >> 3, slot = c & 7;
            int gr = tm + row; gr = gr < M ? gr : M - 1;
            const float* src = A + (size_t)gr * lda + k0 + (slot << 3);
            float4 lo = *reinterpret_cast<const float4*>(src);
            float4 hi = *reinterpret_cast<const float4*>(src + 4);
            bf16x8 pk;
            pk[0]=(__bf16)lo.x; pk[1]=(__bf16)lo.y; pk[2]=(__bf16)lo.z; pk[3]=(__bf16)lo.w;
            pk[4]=(__bf16)hi.x; pk[5]=(__bf16)hi.y; pk[6]=(__bf16)hi.z; pk[7]=(__bf16)hi.w;
            *reinterpret_cast<bf16x8*>(&sA[(row << 7) + ((slot ^ (row & 7)) << 4)]) = pk;
        }
#pragma unroll
        for (int i = 0; i < 4; ++i) {
            int c = tid + (i << 8);
            int row = c >> 3, slot = c & 7;
            int gr = tn + row; gr = gr < N ? gr : N - 1;
            const float* src = B + (size_t)gr * ldb + k0 + (slot << 3);
            float4 lo = *reinterpret_cast<const float4*>(src);
            float4 hi = *reinterpret_cast<const float4*>(src + 4);
            bf16x8 pk;
            pk[0]=(__bf16)lo.x; pk[1]=(__bf16)lo.y; pk[2]=(__bf16)lo.z; pk[3]=(__bf16)lo.w;
            pk[4]=(__bf16)hi.x; pk[5]=(__bf16)hi.y; pk[6]=(__bf16)hi.z; pk[7]=(__bf16)hi.w;
            *reinterpret_cast<bf16x8*>(&sB[(row << 7) + ((slot ^ (row & 7)) << 4)]) = pk;
        }
        __syncthreads();

        bf16x8 af[4][2], bfr[4][2];
#pragma unroll
        for (int kk = 0; kk < 2; ++kk) {
            int sl = (kk << 2) + (lane >> 4);
#pragma unroll
            for (int m = 0; m < 4; ++m) {
                int row = (wr << 6) + (m << 4) + (lane & 15);
                af[m][kk] = *reinterpret_cast<const bf16x8*>(&sA[(row << 7) + ((sl ^ (row & 7)) << 4)]);
            }
#pragma unroll
            for (int n = 0; n < 4; ++n) {
                int row = (wc << 6) + (n << 4) + (lane & 15);
                bfr[n][kk] = *reinterpret_cast<const bf16x8*>(&sB[(row << 7) + ((sl ^ (row & 7)) << 4)]);
            }
        }
#pragma unroll
        for (int kk = 0; kk < 2; ++kk)
#pragma unroll
            for (int m = 0; m < 4; ++m)
#pragma unroll
                for (int n = 0; n < 4; ++n)
                    acc[m][n] = __builtin_amdgcn_mfma_f32_16x16x32_bf16(af[m][kk], bfr[n][kk], acc[m][n], 0, 0, 0);
    }

    // epilogue: C/D layout col=lane&15, row=(lane>>4)*4+j
#pragma unroll
    for (int m = 0; m < 4; ++m) {
        int grow0 = tm + (wr << 6) + (m << 4) + ((lane >> 4) << 2);
#pragma unroll
        for (int n = 0; n < 4; ++n) {
            int gcol = tn + (wc << 6) + (n << 4) + (lane & 15);
            if (gcol < N) {
#pragma unroll
                for (int j = 0; j < 4; ++j) {
                    int grow = grow0 + j;
                    if (grow < M) {
                        size_t o = (size_t)grow * ldc + gcol;
                        float v = acc[m][n][j];
                        if (beta) v += C[o];
                        C[o] = v;
                    }
                }
            }
        }
    }
}

// ---------------- im2col for patch embed: xcol[9216][768] -------------------
__global__ __launch_bounds__(256)
void k_im2col(const float* __restrict__ x, float* __restrict__ xcol)
{
    int id = blockIdx.x * 256 + threadIdx.x;    // (row, ci, kh), 9216*48
    int kh = id & 15;
    int ci = (id >> 4) % 3;
    int row = id / 48;
    int b = row / 576, p = row % 576;
    int py = p / 24, px = p % 24;
    const float* src = x + ((size_t)(b*3 + ci)*384 + py*16 + kh)*384 + px*16;
    float* dst = xcol + (size_t)row*768 + ci*256 + kh*16;
#pragma unroll
    for (int j = 0; j < 4; ++j)
        *reinterpret_cast<float4*>(dst + j*4) = *reinterpret_cast<const float4*>(src + j*4);
}

// --------- assemble tokens: cls+pos / patch+bias+pos -> h_tok[16][577][256] --
__global__ __launch_bounds__(256)
void k_assemble(const float* __restrict__ Ctmp, const float* __restrict__ pb,
                const float* __restrict__ cls, const float* __restrict__ pos,
                float* __restrict__ h_tok)
{
    int i4 = blockIdx.x * 256 + threadIdx.x;    // f4 index, 16*577*64
    int c4 = i4 & 63;
    int tok = (i4 >> 6) % 577;
    int b = i4 / (577*64);
    float4 pv = *reinterpret_cast<const float4*>(pos + tok*256 + c4*4);
    float4 r;
    if (tok == 0) {
        float4 cv = *reinterpret_cast<const float4*>(cls + c4*4);
        r.x = cv.x + pv.x; r.y = cv.y + pv.y; r.z = cv.z + pv.z; r.w = cv.w + pv.w;
    } else {
        float4 t = *reinterpret_cast<const float4*>(Ctmp + (size_t)(b*576 + tok - 1)*256 + c4*4);
        float4 bb = *reinterpret_cast<const float4*>(pb + c4*4);
        r.x = t.x + bb.x + pv.x; r.y = t.y + bb.y + pv.y;
        r.z = t.z + bb.z + pv.z; r.w = t.w + bb.w + pv.w;
    }
    *reinterpret_cast<float4*>(h_tok + (size_t)i4*4) = r;
}

// ---------------- LayerNorm over 256, one wave per row ----------------------
__global__ __launch_bounds__(256)
void k_ln(const float* __restrict__ X, const float* __restrict__ w,
          const float* __restrict__ bb, float* __restrict__ O)
{
    int lane = threadIdx.x & 63;
    int row = blockIdx.x * 4 + (threadIdx.x >> 6);
    const float4 v = *reinterpret_cast<const float4*>(X + (size_t)row*256 + lane*4);
    float s1 = v.x + v.y + v.z + v.w;
    float s2 = v.x*v.x + v.y*v.y + v.z*v.z + v.w*v.w;
#pragma unroll
    for (int o2 = 32; o2; o2 >>= 1) { s1 += __shfl_xor(s1, o2); s2 += __shfl_xor(s2, o2); }
    float mu = s1 * (1.f/256.f);
    float var = s2 * (1.f/256.f) - mu*mu;
    float rs = rsqrtf(var + 1e-5f);
    float4 wv = *reinterpret_cast<const float4*>(w + lane*4);
    float4 bv = *reinterpret_cast<const float4*>(bb + lane*4);
    float4 o;
    o.x = (v.x - mu)*rs*wv.x + bv.x;
    o.y = (v.y - mu)*rs*wv.y + bv.y;
    o.z = (v.z - mu)*rs*wv.z + bv.z;
    o.w = (v.w - mu)*rs*wv.w + bv.w;
    *reinterpret_cast<float4*>(O + (size_t)row*256 + lane*4) = o;
}

// ------------- causal depthwise conv K=4 + SiLU: xz[:, :512] -> xi ----------
__global__ __launch_bounds__(256)
void k_conv(const float* __restrict__ xz, const float* __restrict__ cw,
            const float* __restrict__ cb, float* __restrict__ xi)
{
    int gw = blockIdx.x * 4 + (threadIdx.x >> 6);   // 16*8*73 waves
    int lane = threadIdx.x & 63;
    int tc = gw % 73;
    int eg = (gw / 73) & 7;
    int b  = gw / (73*8);
    int e = eg*64 + lane;
    float4 wv = *reinterpret_cast<const float4*>(cw + e*4);
    float bias = cb[e];
    int t0 = tc * 8;
    float xv[11];
#pragma unroll
    for (int j = 0; j < 11; ++j) {
        int t = t0 - 3 + j;
        xv[j] = (t >= 0 && t < 577) ? xz[(size_t)(b*577 + t)*1024 + e] : 0.f;
    }
#pragma unroll
    for (int j = 0; j < 8; ++j) {
        int t = t0 + j;
        if (t < 577) {
            float a = wv.x*xv[j] + wv.y*xv[j+1] + wv.z*xv[j+2] + wv.w*xv[j+3] + bias;
            float sgm = 1.f / (1.f + __expf(-a));
            xi[(size_t)(b*577 + t)*512 + e] = a * sgm;
        }
    }
}

// -------- dt_proj (K=16) + softplus: dbl[:, :16] @ dtw^T + dtb -> dt --------
__global__ __launch_bounds__(256)
void k_dtfuse(const float* __restrict__ dbl, const float* __restrict__ dtw,
              const float* __restrict__ dtb, float* __restrict__ dt)
{
    int row = blockIdx.x >> 1;
    int e = ((blockIdx.x & 1) << 8) + threadIdx.x;
    const float* dr = dbl + (size_t)row*144;
    const float* wp = dtw + e*16;
    float accv = dtb[e];
#pragma unroll
    for (int r = 0; r < 16; r += 4) {
        float4 wv = *reinterpret_cast<const float4*>(wp + r);
        accv += wv.x*dr[r] + wv.y*dr[r+1] + wv.z*dr[r+2] + wv.w*dr[r+3];
    }
    float sp = accv > 20.f ? accv : log1pf(__expf(accv));
    dt[(size_t)row*512 + e] = sp;
}

// ------------- selective scan: wave = (b, d), lane = state s ----------------
__global__ __launch_bounds__(1024)
void k_scan(const float* __restrict__ dt, const float* __restrict__ xi,
            const float* __restrict__ dbl, const float* __restrict__ A_log,
            const float* __restrict__ Dp, float* __restrict__ y)
{
    int lane = threadIdx.x & 63;
    int wave = threadIdx.x >> 6;              // 0..15
    int b = blockIdx.x >> 5;                  // 32 blocks per batch
    int d = (blockIdx.x & 31) * 16 + wave;    // 0..511
    float a_nat = -__expf(A_log[d*64 + lane]);   // A[d][s]
    float dpv = Dp[d];
    size_t row0 = (size_t)b * 577;
    const float* dtp = dt  + row0*512 + d;
    const float* xip = xi  + row0*512 + d;
    const float* Bp  = dbl + row0*144 + 16 + lane;
    const float* Cp  = Bp + 64;
    float* yp = y + row0*512 + d;
    float h = 0.f;
    for (int t = 0; t < 577; ++t) {
        float dtv = dtp[(size_t)t*512];
        float uv  = xip[(size_t)t*512];
        float Bv  = Bp[(size_t)t*144];
        float Cv  = Cp[(size_t)t*144];
        float dA  = __expf(dtv * a_nat);
        h = __builtin_fmaf(dA, h, dtv*uv*Bv);
        float p = h * Cv;
        p += __shfl_xor(p, 32); p += __shfl_xor(p, 16); p += __shfl_xor(p, 8);
        p += __shfl_xor(p, 4);  p += __shfl_xor(p, 2);  p += __shfl_xor(p, 1);
        if (lane == 0) yp[(size_t)t*512] = __builtin_fmaf(uv, dpv, p);
    }
}

// ---------------- y *= silu(z)  (in place on y) -----------------------------
__global__ __launch_bounds__(256)
void k_gate(float* __restrict__ y, const float* __restrict__ xz)
{
    int i4 = blockIdx.x * 256 + threadIdx.x;   // 9232*128 f4
    int row = i4 >> 7;
    int c4 = i4 & 127;
    float4 yv = *reinterpret_cast<float4*>(y + (size_t)i4*4);
    const float4 zv = *reinterpret_cast<const float4*>(xz + (size_t)row*1024 + 512 + c4*4);
    float4 o;
    o.x = yv.x * (zv.x / (1.f + __expf(-zv.x)));
    o.y = yv.y * (zv.y / (1.f + __expf(-zv.y)));
    o.z = yv.z * (zv.z / (1.f + __expf(-zv.z)));
    o.w = yv.w * (zv.w / (1.f + __expf(-zv.w)));
    *reinterpret_cast<float4*>(y + (size_t)i4*4) = o;
}

// ---------------- final LN (cls token) + head -------------------------------
__global__ __launch_bounds__(256)
void k_head(const float* __restrict__ h_tok, const float* __restrict__ fw,
            const float* __restrict__ fb, const float* __restrict__ hw,
            const float* __restrict__ hb, float* __restrict__ out)
{
    int b = blockIdx.x, tid = threadIdx.x;
    __shared__ float sv[256];
    __shared__ float sr[16];
    float v = h_tok[(size_t)b*577*256 + tid];
    float s1 = v, s2 = v*v;
#pragma unroll
    for (int o2 = 32; o2; o2 >>= 1) { s1 += __shfl_xor(s1, o2); s2 += __shfl_xor(s2, o2); }
    int wave = tid >> 6;
    if ((tid & 63) == 0) { sr[wave] = s1; sr[wave + 8] = s2; }
    __syncthreads();
    float t1 = sr[0] + sr[1] + sr[2] + sr[3];
    float t2 = sr[8] + sr[9] + sr[10] + sr[11];
    float mu = t1 * (1.f/256.f);
    float var = t2 * (1.f/256.f) - mu*mu;
    float rs = rsqrtf(var + 1e-5f);
    sv[tid] = (v - mu)*rs*fw[tid] + fb[tid];
    __syncthreads();
    if (tid < 10) {
        float acc = hb[tid];
        for (int d2 = 0; d2 < 256; ++d2) acc += sv[d2]*hw[tid*256 + d2];
        out[b*10 + tid] = acc;
    }
}

extern "C" void kernel_launch(void* const* d_in, const int* in_sizes, int n_in,
                              void* d_out, int out_size, void* d_ws, size_t ws_size,
                              hipStream_t stream)
{
    const float* x         = (const float*)d_in[0];
    const float* patch_w   = (const float*)d_in[1];
    const float* patch_b   = (const float*)d_in[2];
    const float* cls_tok   = (const float*)d_in[3];
    const float* pos_emb   = (const float*)d_in[4];
    const float* norm_w    = (const float*)d_in[5];
    const float* norm_b    = (const float*)d_in[6];
    const float* in_proj_w = (const float*)d_in[7];
    const float* conv_w    = (const float*)d_in[8];
    const float* conv_b    = (const float*)d_in[9];
    const float* x_proj_w  = (const float*)d_in[10];
    const float* dt_proj_w = (const float*)d_in[11];
    const float* dt_proj_b = (const float*)d_in[12];
    const float* A_log     = (const float*)d_in[13];
    const float* D_ssm     = (const float*)d_in[14];
    const float* out_proj_w= (const float*)d_in[15];
    const float* fnorm_w   = (const float*)d_in[16];
    const float* fnorm_b   = (const float*)d_in[17];
    const float* head_w    = (const float*)d_in[18];
    const float* head_b    = (const float*)d_in[19];
    float* out = (float*)d_out;

    char* ws = (char*)d_ws;
    size_t off = 0;
    auto carve = [&](size_t bytes) -> float* {
        float* p = (float*)(ws + off);
        off += (bytes + 255) & ~(size_t)255;
        return p;
    };
    float* h_tok = carve((size_t)NROWS*DM*4);     //  9.45 MB
    float* xln   = carve((size_t)NROWS*DM*4);     //  9.45 MB
    float* xz    = carve((size_t)NROWS*1024*4);   // 37.8 MB (pre-loop alias: xcol 28.3 MB)
    float* xi    = carve((size_t)NROWS*DI*4);     // 18.9 MB (pre-loop alias: Ctmp 9.4 MB)
    float* dbl   = carve((size_t)NROWS*144*4);    //  5.3 MB
    float* dt    = carve((size_t)NROWS*DI*4);     // 18.9 MB
    float* yb    = carve((size_t)NROWS*DI*4);     // 18.9 MB
    float* xcol  = xz;
    float* Ctmp  = xi;

    // ---- patch embed ----
    k_im2col<<<1728, 256, 0, stream>>>(x, xcol);
    {
        dim3 g(2, 72);
        k_gemm<<<g, 256, 0, stream>>>(xcol, 768, patch_w, 768, Ctmp, 256, PROWS, 256, 768, 0);
    }
    k_assemble<<<2308, 256, 0, stream>>>(Ctmp, patch_b, cls_tok, pos_emb, h_tok);

    // ---- 6 mamba blocks ----
    for (int i = 0; i < 6; ++i) {
        k_ln<<<2308, 256, 0, stream>>>(h_tok, norm_w + i*DM, norm_b + i*DM, xln);
        {
            dim3 g(8, 73);
            k_gemm<<<g, 256, 0, stream>>>(xln, DM, in_proj_w + (size_t)i*1024*DM, DM,
                                          xz, 1024, NROWS, 1024, DM, 0);
        }
        k_conv<<<2336, 256, 0, stream>>>(xz, conv_w + (size_t)i*DI*4, conv_b + i*DI, xi);
        {
            dim3 g(2, 73);
            k_gemm<<<g, 256, 0, stream>>>(xi, DI, x_proj_w + (size_t)i*144*DI, DI,
                                          dbl, 144, NROWS, 144, DI, 0);
        }
        k_dtfuse<<<NROWS*2, 256, 0, stream>>>(dbl, dt_proj_w + (size_t)i*DI*16, dt_proj_b + i*DI, dt);
        k_scan<<<512, 1024, 0, stream>>>(dt, xi, dbl, A_log + (size_t)i*DI*DS_, D_ssm + i*DI, yb);
        k_gate<<<4616, 256, 0, stream>>>(yb, xz);
        {
            dim3 g(2, 73);
            k_gemm<<<g, 256, 0, stream>>>(yb, DI, out_proj_w + (size_t)i*DM*DI, DI,
                                          h_tok, DM, NROWS, DM, DI, 1);
        }
    }
    k_head<<<16, 256, 0, stream>>>(h_tok, fnorm_w, fnorm_b, head_w, head_b, out);
}

// Round 2
// 1832.772 us; speedup vs baseline: 1.6104x; 1.6104x over previous
//
#include <hip/hip_runtime.h>
#include <hip/hip_bf16.h>
#include <cstdint>
#include <cstddef>

#define L_TOK 577
#define DM 256
#define DI 512
#define DS_ 64
#define NROWS (16*577)      // 9232
#define PROWS (16*576)      // 9216

typedef float f32x4v __attribute__((ext_vector_type(4)));
typedef __bf16 bf16x8 __attribute__((ext_vector_type(8)));

__device__ __forceinline__ float fast_exp2(float x) {
#if __has_builtin(__builtin_amdgcn_exp2f)
    return __builtin_amdgcn_exp2f(x);
#else
    return __expf(x * 0.6931471805599453f);
#endif
}

// 64-lane sum via DPP row ops; valid result in lane 63.
__device__ __forceinline__ float dpp_sum64(float x) {
#define DPP_STEP(ctrl) \
    x += __builtin_bit_cast(float, __builtin_amdgcn_update_dpp( \
        0, __builtin_bit_cast(int, x), ctrl, 0xf, 0xf, true))
    DPP_STEP(0x111);  // row_shr:1
    DPP_STEP(0x112);  // row_shr:2
    DPP_STEP(0x114);  // row_shr:4
    DPP_STEP(0x118);  // row_shr:8
    DPP_STEP(0x142);  // row_bcast:15
    DPP_STEP(0x143);  // row_bcast:31
#undef DPP_STEP
    return x;
}

// ---------------- GEMM: C[M,N] = A[M,K] * B[N,K]^T  (+C if beta) -------------
__global__ __launch_bounds__(256)
void k_gemm(const float* __restrict__ A, int lda,
            const float* __restrict__ B, int ldb,
            float* __restrict__ C, int ldc,
            int M, int N, int K, int beta)
{
    __shared__ char sA[128*64*2];
    __shared__ char sB[128*64*2];
    const int tid  = threadIdx.x;
    const int lane = tid & 63;
    const int wave = tid >> 6;
    const int wr = wave >> 1, wc = wave & 1;
    const int tm = blockIdx.y * 128, tn = blockIdx.x * 128;

    f32x4v acc[4][4];
#pragma unroll
    for (int m = 0; m < 4; ++m)
#pragma unroll
        for (int n = 0; n < 4; ++n) acc[m][n] = (f32x4v){0.f, 0.f, 0.f, 0.f};

    const int nk = K >> 6;
    for (int kt = 0; kt < nk; ++kt) {
        const int k0 = kt << 6;
        __syncthreads();
#pragma unroll
        for (int i = 0; i < 4; ++i) {
            int c = tid + (i << 8);
            int row = c >> 3, slot = c & 7;
            int gr = tm + row; gr = gr < M ? gr : M - 1;
            const float* src = A + (size_t)gr * lda + k0 + (slot << 3);
            float4 lo = *reinterpret_cast<const float4*>(src);
            float4 hi = *reinterpret_cast<const float4*>(src + 4);
            bf16x8 pk;
            pk[0]=(__bf16)lo.x; pk[1]=(__bf16)lo.y; pk[2]=(__bf16)lo.z; pk[3]=(__bf16)lo.w;
            pk[4]=(__bf16)hi.x; pk[5]=(__bf16)hi.y; pk[6]=(__bf16)hi.z; pk[7]=(__bf16)hi.w;
            *reinterpret_cast<bf16x8*>(&sA[(row << 7) + ((slot ^ (row & 7)) << 4)]) = pk;
        }
#pragma unroll
        for (int i = 0; i < 4; ++i) {
            int c = tid + (i << 8);
            int row = c >> 3, slot = c & 7;
            int gr = tn + row; gr = gr < N ? gr : N - 1;
            const float* src = B + (size_t)gr * ldb + k0 + (slot << 3);
            float4 lo = *reinterpret_cast<const float4*>(src);
            float4 hi = *reinterpret_cast<const float4*>(src + 4);
            bf16x8 pk;
            pk[0]=(__bf16)lo.x; pk[1]=(__bf16)lo.y; pk[2]=(__bf16)lo.z; pk[3]=(__bf16)lo.w;
            pk[4]=(__bf16)hi.x; pk[5]=(__bf16)hi.y; pk[6]=(__bf16)hi.z; pk[7]=(__bf16)hi.w;
            *reinterpret_cast<bf16x8*>(&sB[(row << 7) + ((slot ^ (row & 7)) << 4)]) = pk;
        }
        __syncthreads();

        bf16x8 af[4][2], bfr[4][2];
#pragma unroll
        for (int kk = 0; kk < 2; ++kk) {
            int sl = (kk << 2) + (lane >> 4);
#pragma unroll
            for (int m = 0; m < 4; ++m) {
                int row = (wr << 6) + (m << 4) + (lane & 15);
                af[m][kk] = *reinterpret_cast<const bf16x8*>(&sA[(row << 7) + ((sl ^ (row & 7)) << 4)]);
            }
#pragma unroll
            for (int n = 0; n < 4; ++n) {
                int row = (wc << 6) + (n << 4) + (lane & 15);
                bfr[n][kk] = *reinterpret_cast<const bf16x8*>(&sB[(row << 7) + ((sl ^ (row & 7)) << 4)]);
            }
        }
#pragma unroll
        for (int kk = 0; kk < 2; ++kk)
#pragma unroll
            for (int m = 0; m < 4; ++m)
#pragma unroll
                for (int n = 0; n < 4; ++n)
                    acc[m][n] = __builtin_amdgcn_mfma_f32_16x16x32_bf16(af[m][kk], bfr[n][kk], acc[m][n], 0, 0, 0);
    }

#pragma unroll
    for (int m = 0; m < 4; ++m) {
        int grow0 = tm + (wr << 6) + (m << 4) + ((lane >> 4) << 2);
#pragma unroll
        for (int n = 0; n < 4; ++n) {
            int gcol = tn + (wc << 6) + (n << 4) + (lane & 15);
            if (gcol < N) {
#pragma unroll
                for (int j = 0; j < 4; ++j) {
                    int grow = grow0 + j;
                    if (grow < M) {
                        size_t o = (size_t)grow * ldc + gcol;
                        float v = acc[m][n][j];
                        if (beta) v += C[o];
                        C[o] = v;
                    }
                }
            }
        }
    }
}

// ---------------- im2col for patch embed: xcol[9216][768] -------------------
__global__ __launch_bounds__(256)
void k_im2col(const float* __restrict__ x, float* __restrict__ xcol)
{
    int id = blockIdx.x * 256 + threadIdx.x;
    int kh = id & 15;
    int ci = (id >> 4) % 3;
    int row = id / 48;
    int b = row / 576, p = row % 576;
    int py = p / 24, px = p % 24;
    const float* src = x + ((size_t)(b*3 + ci)*384 + py*16 + kh)*384 + px*16;
    float* dst = xcol + (size_t)row*768 + ci*256 + kh*16;
#pragma unroll
    for (int j = 0; j < 4; ++j)
        *reinterpret_cast<float4*>(dst + j*4) = *reinterpret_cast<const float4*>(src + j*4);
}

// --------- assemble tokens: cls+pos / patch+bias+pos -> h_tok ----------------
__global__ __launch_bounds__(256)
void k_assemble(const float* __restrict__ Ctmp, const float* __restrict__ pb,
                const float* __restrict__ cls, const float* __restrict__ pos,
                float* __restrict__ h_tok)
{
    int i4 = blockIdx.x * 256 + threadIdx.x;
    int c4 = i4 & 63;
    int tok = (i4 >> 6) % 577;
    int b = i4 / (577*64);
    float4 pv = *reinterpret_cast<const float4*>(pos + tok*256 + c4*4);
    float4 r;
    if (tok == 0) {
        float4 cv = *reinterpret_cast<const float4*>(cls + c4*4);
        r.x = cv.x + pv.x; r.y = cv.y + pv.y; r.z = cv.z + pv.z; r.w = cv.w + pv.w;
    } else {
        float4 t = *reinterpret_cast<const float4*>(Ctmp + (size_t)(b*576 + tok - 1)*256 + c4*4);
        float4 bb = *reinterpret_cast<const float4*>(pb + c4*4);
        r.x = t.x + bb.x + pv.x; r.y = t.y + bb.y + pv.y;
        r.z = t.z + bb.z + pv.z; r.w = t.w + bb.w + pv.w;
    }
    *reinterpret_cast<float4*>(h_tok + (size_t)i4*4) = r;
}

// ---------------- LayerNorm over 256, one wave per row ----------------------
__global__ __launch_bounds__(256)
void k_ln(const float* __restrict__ X, const float* __restrict__ w,
          const float* __restrict__ bb, float* __restrict__ O)
{
    int lane = threadIdx.x & 63;
    int row = blockIdx.x * 4 + (threadIdx.x >> 6);
    const float4 v = *reinterpret_cast<const float4*>(X + (size_t)row*256 + lane*4);
    float s1 = v.x + v.y + v.z + v.w;
    float s2 = v.x*v.x + v.y*v.y + v.z*v.z + v.w*v.w;
#pragma unroll
    for (int o2 = 32; o2; o2 >>= 1) { s1 += __shfl_xor(s1, o2); s2 += __shfl_xor(s2, o2); }
    float mu = s1 * (1.f/256.f);
    float var = s2 * (1.f/256.f) - mu*mu;
    float rs = rsqrtf(var + 1e-5f);
    float4 wv = *reinterpret_cast<const float4*>(w + lane*4);
    float4 bv = *reinterpret_cast<const float4*>(bb + lane*4);
    float4 o;
    o.x = (v.x - mu)*rs*wv.x + bv.x;
    o.y = (v.y - mu)*rs*wv.y + bv.y;
    o.z = (v.z - mu)*rs*wv.z + bv.z;
    o.w = (v.w - mu)*rs*wv.w + bv.w;
    *reinterpret_cast<float4*>(O + (size_t)row*256 + lane*4) = o;
}

// ------------- causal depthwise conv K=4 + SiLU: xz[:, :512] -> xi ----------
__global__ __launch_bounds__(256)
void k_conv(const float* __restrict__ xz, const float* __restrict__ cw,
            const float* __restrict__ cb, float* __restrict__ xi)
{
    int gw = blockIdx.x * 4 + (threadIdx.x >> 6);
    int lane = threadIdx.x & 63;
    int tc = gw % 73;
    int eg = (gw / 73) & 7;
    int b  = gw / (73*8);
    int e = eg*64 + lane;
    float4 wv = *reinterpret_cast<const float4*>(cw + e*4);
    float bias = cb[e];
    int t0 = tc * 8;
    float xv[11];
#pragma unroll
    for (int j = 0; j < 11; ++j) {
        int t = t0 - 3 + j;
        xv[j] = (t >= 0 && t < 577) ? xz[(size_t)(b*577 + t)*1024 + e] : 0.f;
    }
#pragma unroll
    for (int j = 0; j < 8; ++j) {
        int t = t0 + j;
        if (t < 577) {
            float a = wv.x*xv[j] + wv.y*xv[j+1] + wv.z*xv[j+2] + wv.w*xv[j+3] + bias;
            float sgm = 1.f / (1.f + __expf(-a));
            xi[(size_t)(b*577 + t)*512 + e] = a * sgm;
        }
    }
}

// ---- dt_proj (K=16) + softplus; writes tri2[row][d] = {dt, dt*u} -----------
__global__ __launch_bounds__(256)
void k_dtfuse(const float* __restrict__ dbl, const float* __restrict__ dtw,
              const float* __restrict__ dtb, const float* __restrict__ xi,
              float* __restrict__ tri2)
{
    int row = blockIdx.x >> 1;
    int e = ((blockIdx.x & 1) << 8) + threadIdx.x;
    const float* dr = dbl + (size_t)row*144;
    const float* wp = dtw + e*16;
    float accv = dtb[e];
#pragma unroll
    for (int r = 0; r < 16; r += 4) {
        float4 wv = *reinterpret_cast<const float4*>(wp + r);
        accv += wv.x*dr[r] + wv.y*dr[r+1] + wv.z*dr[r+2] + wv.w*dr[r+3];
    }
    float sp = accv > 20.f ? accv : log1pf(__expf(accv));
    float u = xi[(size_t)row*512 + e];
    float2 o; o.x = sp; o.y = sp * u;
    *reinterpret_cast<float2*>(tri2 + ((size_t)row*512 + e)*2) = o;
}

// ------------- selective scan: wave = (b, d), lane = state s ----------------
// tri2 read via wave-uniform pointer (scalar loads); B/C coalesced VMEM;
// DPP 64-lane reduce; store from lane 63. u*D term applied in k_gate.
__global__ __launch_bounds__(256, 8)
void k_scan(const float* __restrict__ tri2, const float* __restrict__ dbl,
            const float* __restrict__ A_log, float* __restrict__ y)
{
    const int lane = threadIdx.x & 63;
    const int wv = __builtin_amdgcn_readfirstlane(threadIdx.x >> 6);      // 0..3
    const int bb = blockIdx.x >> 7;                                       // 0..15
    const int d  = __builtin_amdgcn_readfirstlane(((blockIdx.x & 127) << 2) + wv);
    const float alog2 = -__expf(A_log[(size_t)d*64 + lane]) * 1.44269504f;
    const size_t row0 = (size_t)bb * 577;
    const float2* trip = reinterpret_cast<const float2*>(tri2) + row0*512 + d;  // uniform
    const float* Bb = dbl + row0*144 + 16 + lane;
    float* yp = y + row0*512 + d;
    float h = 0.f;
    int t = 0;
    for (; t < 576; t += 4) {
        float p[4];
#pragma unroll
        for (int i = 0; i < 4; ++i) {
            float2 tr = trip[(size_t)(t+i)*512];
            float Bv = Bb[(size_t)(t+i)*144];
            float Cv = Bb[(size_t)(t+i)*144 + 64];
            float dA = fast_exp2(tr.x * alog2);
            h = __builtin_fmaf(dA, h, tr.y * Bv);
            p[i] = h * Cv;
        }
#pragma unroll
        for (int i = 0; i < 4; ++i) p[i] = dpp_sum64(p[i]);
        if (lane == 63) {
#pragma unroll
            for (int i = 0; i < 4; ++i) yp[(size_t)(t+i)*512] = p[i];
        }
    }
    {   // tail t = 576
        float2 tr = trip[(size_t)t*512];
        float Bv = Bb[(size_t)t*144];
        float Cv = Bb[(size_t)t*144 + 64];
        float dA = fast_exp2(tr.x * alog2);
        h = __builtin_fmaf(dA, h, tr.y * Bv);
        float p = dpp_sum64(h * Cv);
        if (lane == 63) yp[(size_t)t*512] = p;
    }
}

// ------------- y = (y + u*D) * silu(z)  (in place on y) ---------------------
__global__ __launch_bounds__(256)
void k_gate(float* __restrict__ y, const float* __restrict__ xz,
            const float* __restrict__ xi, const float* __restrict__ Dp)
{
    int i4 = blockIdx.x * 256 + threadIdx.x;   // 9232*128 f4
    int row = i4 >> 7;
    int c4 = i4 & 127;
    float4 yv = *reinterpret_cast<float4*>(y + (size_t)i4*4);
    float4 uv = *reinterpret_cast<const float4*>(xi + (size_t)i4*4);
    float4 dv = *reinterpret_cast<const float4*>(Dp + c4*4);
    const float4 zv = *reinterpret_cast<const float4*>(xz + (size_t)row*1024 + 512 + c4*4);
    float4 o;
    o.x = (yv.x + uv.x*dv.x) * (zv.x / (1.f + __expf(-zv.x)));
    o.y = (yv.y + uv.y*dv.y) * (zv.y / (1.f + __expf(-zv.y)));
    o.z = (yv.z + uv.z*dv.z) * (zv.z / (1.f + __expf(-zv.z)));
    o.w = (yv.w + uv.w*dv.w) * (zv.w / (1.f + __expf(-zv.w)));
    *reinterpret_cast<float4*>(y + (size_t)i4*4) = o;
}

// ---------------- final LN (cls token) + head -------------------------------
__global__ __launch_bounds__(256)
void k_head(const float* __restrict__ h_tok, const float* __restrict__ fw,
            const float* __restrict__ fb, const float* __restrict__ hw,
            const float* __restrict__ hb, float* __restrict__ out)
{
    int b = blockIdx.x, tid = threadIdx.x;
    __shared__ float sv[256];
    __shared__ float sr[16];
    float v = h_tok[(size_t)b*577*256 + tid];
    float s1 = v, s2 = v*v;
#pragma unroll
    for (int o2 = 32; o2; o2 >>= 1) { s1 += __shfl_xor(s1, o2); s2 += __shfl_xor(s2, o2); }
    int wave = tid >> 6;
    if ((tid & 63) == 0) { sr[wave] = s1; sr[wave + 8] = s2; }
    __syncthreads();
    float t1 = sr[0] + sr[1] + sr[2] + sr[3];
    float t2 = sr[8] + sr[9] + sr[10] + sr[11];
    float mu = t1 * (1.f/256.f);
    float var = t2 * (1.f/256.f) - mu*mu;
    float rs = rsqrtf(var + 1e-5f);
    sv[tid] = (v - mu)*rs*fw[tid] + fb[tid];
    __syncthreads();
    if (tid < 10) {
        float acc = hb[tid];
        for (int d2 = 0; d2 < 256; ++d2) acc += sv[d2]*hw[tid*256 + d2];
        out[b*10 + tid] = acc;
    }
}

extern "C" void kernel_launch(void* const* d_in, const int* in_sizes, int n_in,
                              void* d_out, int out_size, void* d_ws, size_t ws_size,
                              hipStream_t stream)
{
    const float* x         = (const float*)d_in[0];
    const float* patch_w   = (const float*)d_in[1];
    const float* patch_b   = (const float*)d_in[2];
    const float* cls_tok   = (const float*)d_in[3];
    const float* pos_emb   = (const float*)d_in[4];
    const float* norm_w    = (const float*)d_in[5];
    const float* norm_b    = (const float*)d_in[6];
    const float* in_proj_w = (const float*)d_in[7];
    const float* conv_w    = (const float*)d_in[8];
    const float* conv_b    = (const float*)d_in[9];
    const float* x_proj_w  = (const float*)d_in[10];
    const float* dt_proj_w = (const float*)d_in[11];
    const float* dt_proj_b = (const float*)d_in[12];
    const float* A_log     = (const float*)d_in[13];
    const float* D_ssm     = (const float*)d_in[14];
    const float* out_proj_w= (const float*)d_in[15];
    const float* fnorm_w   = (const float*)d_in[16];
    const float* fnorm_b   = (const float*)d_in[17];
    const float* head_w    = (const float*)d_in[18];
    const float* head_b    = (const float*)d_in[19];
    float* out = (float*)d_out;

    char* ws = (char*)d_ws;
    size_t off = 0;
    auto carve = [&](size_t bytes) -> float* {
        float* p = (float*)(ws + off);
        off += (bytes + 255) & ~(size_t)255;
        return p;
    };
    float* h_tok = carve((size_t)NROWS*DM*4);       //  9.45 MB
    float* xln   = carve((size_t)NROWS*DM*4);       //  9.45 MB
    float* xz    = carve((size_t)NROWS*1024*4);     // 37.8 MB (alias: xcol)
    float* xi    = carve((size_t)NROWS*DI*4);       // 18.9 MB (alias: Ctmp)
    float* dbl   = carve((size_t)NROWS*144*4);      //  5.3 MB
    float* tri2  = carve((size_t)NROWS*DI*2*4);     // 37.8 MB
    float* yb    = carve((size_t)NROWS*DI*4);       // 18.9 MB
    float* xcol  = xz;
    float* Ctmp  = xi;

    // ---- patch embed ----
    k_im2col<<<1728, 256, 0, stream>>>(x, xcol);
    {
        dim3 g(2, 72);
        k_gemm<<<g, 256, 0, stream>>>(xcol, 768, patch_w, 768, Ctmp, 256, PROWS, 256, 768, 0);
    }
    k_assemble<<<2308, 256, 0, stream>>>(Ctmp, patch_b, cls_tok, pos_emb, h_tok);

    // ---- 6 mamba blocks ----
    for (int i = 0; i < 6; ++i) {
        k_ln<<<2308, 256, 0, stream>>>(h_tok, norm_w + i*DM, norm_b + i*DM, xln);
        {
            dim3 g(8, 73);
            k_gemm<<<g, 256, 0, stream>>>(xln, DM, in_proj_w + (size_t)i*1024*DM, DM,
                                          xz, 1024, NROWS, 1024, DM, 0);
        }
        k_conv<<<2336, 256, 0, stream>>>(xz, conv_w + (size_t)i*DI*4, conv_b + i*DI, xi);
        {
            dim3 g(2, 73);
            k_gemm<<<g, 256, 0, stream>>>(xi, DI, x_proj_w + (size_t)i*144*DI, DI,
                                          dbl, 144, NROWS, 144, DI, 0);
        }
        k_dtfuse<<<NROWS*2, 256, 0, stream>>>(dbl, dt_proj_w + (size_t)i*DI*16, dt_proj_b + i*DI,
                                              xi, tri2);
        k_scan<<<2048, 256, 0, stream>>>(tri2, dbl, A_log + (size_t)i*DI*DS_, yb);
        k_gate<<<4616, 256, 0, stream>>>(yb, xz, xi, D_ssm + i*DI);
        {
            dim3 g(2, 73);
            k_gemm<<<g, 256, 0, stream>>>(yb, DI, out_proj_w + (size_t)i*DM*DI, DI,
                                          h_tok, DM, NROWS, DM, DI, 1);
        }
    }
    k_head<<<16, 256, 0, stream>>>(h_tok, fnorm_w, fnorm_b, head_w, head_b, out);
}